// Round 1
// baseline (788.057 us; speedup 1.0000x reference)
//
#include <hip/hip_runtime.h>
#include <math.h>

#define NR   8
#define NK   10
#define ND   256
#define NDL  10
#define NB   4096

// ws layout: Gp[r][k][d1*10+d2], R*K*100 floats = 32 KB.
// Gp = 10*I - 5*G  (G = Us_rk^T Us_rk), so softmax logit = z^T Gp z
// (the 5*||x||^2 term is constant over k and cancels in softmax).

__global__ __launch_bounds__(128) void gram_kernel(const float* __restrict__ Us,
                                                   float* __restrict__ Gp) {
    int rk = blockIdx.x;                       // 0..79
    const float* U = Us + (size_t)rk * ND * NDL;
    __shared__ float u[ND * NDL];              // 10 KB
    for (int i = threadIdx.x; i < ND * NDL; i += blockDim.x) u[i] = U[i];
    __syncthreads();
    int e = threadIdx.x;
    if (e < NDL * NDL) {
        int d1 = e / NDL, d2 = e % NDL;
        float acc = 0.f;
        #pragma unroll 8
        for (int Di = 0; Di < ND; ++Di)
            acc += u[Di * NDL + d1] * u[Di * NDL + d2];
        Gp[(size_t)rk * (NDL * NDL) + e] = (d1 == d2 ? 10.0f : 0.0f) - 5.0f * acc;
    }
}

// Block = 256 threads: 64 local b's x 4 lanes each (lane t owns D-slice [t*64, t*64+64)).
// Grid = (B/64, R).
__global__ __launch_bounds__(256) void ksub_kernel(const float* __restrict__ x,
                                                   const float* __restrict__ Us,
                                                   const float* __restrict__ Gp,
                                                   float* __restrict__ out) {
    __shared__ float gp[NK * NDL * NDL];       // 1000 floats, Gp for this r
    __shared__ float zs[64 * 120];             // per local-b: 10 k-rows, stride 12

    const int tid = threadIdx.x;
    const int bl  = tid >> 2;                  // local b: 0..63
    const int t   = tid & 3;                   // D-slice: 0..3
    const int r   = blockIdx.y;
    const int b   = blockIdx.x * 64 + bl;

    for (int i = tid; i < NK * NDL * NDL; i += 256)
        gp[i] = Gp[(size_t)r * (NK * NDL * NDL) + i];
    __syncthreads();

    // ---- load x slice into registers (16 x float4, 16B aligned) ----
    float xr[64];
    {
        const float4* xp = (const float4*)(x + (size_t)b * ND + t * 64);
        #pragma unroll
        for (int i = 0; i < 16; ++i) {
            float4 v = xp[i];
            xr[4*i+0] = v.x; xr[4*i+1] = v.y; xr[4*i+2] = v.z; xr[4*i+3] = v.w;
        }
    }

    float* zrow = &zs[bl * 120];

    // ---- phase 1: z_k = Us_rk^T x  (partial over this lane's 64 D's) ----
    for (int k = 0; k < NK; ++k) {
        // Us[r][k][t*64 + D][d]; D stepped by 2 -> 20 contiguous floats, 16B aligned
        const float4* Up = (const float4*)(Us + ((size_t)(r * NK + k) * ND + t * 64) * NDL);
        float zk[10];
        #pragma unroll
        for (int d = 0; d < 10; ++d) zk[d] = 0.f;
        #pragma unroll
        for (int i = 0; i < 32; ++i) {
            float4 u0 = Up[i*5+0];
            float4 u1 = Up[i*5+1];
            float4 u2 = Up[i*5+2];
            float4 u3 = Up[i*5+3];
            float4 u4 = Up[i*5+4];
            float xa = xr[2*i], xb = xr[2*i+1];
            zk[0] += xa*u0.x; zk[1] += xa*u0.y; zk[2] += xa*u0.z; zk[3] += xa*u0.w;
            zk[4] += xa*u1.x; zk[5] += xa*u1.y; zk[6] += xa*u1.z; zk[7] += xa*u1.w;
            zk[8] += xa*u2.x; zk[9] += xa*u2.y;
            zk[0] += xb*u2.z; zk[1] += xb*u2.w;
            zk[2] += xb*u3.x; zk[3] += xb*u3.y; zk[4] += xb*u3.z; zk[5] += xb*u3.w;
            zk[6] += xb*u4.x; zk[7] += xb*u4.y; zk[8] += xb*u4.z; zk[9] += xb*u4.w;
        }
        // reduce partials across the 4 lanes of this b-group (butterfly)
        #pragma unroll
        for (int d = 0; d < 10; ++d) {
            zk[d] += __shfl_xor(zk[d], 1);
            zk[d] += __shfl_xor(zk[d], 2);
        }
        if (t == 0) {
            float* zp = zrow + k * 12;
            zp[0] = zk[0]; zp[1] = zk[1]; zp[2] = zk[2]; zp[3] = zk[3]; zp[4] = zk[4];
            zp[5] = zk[5]; zp[6] = zk[6]; zp[7] = zk[7]; zp[8] = zk[8]; zp[9] = zk[9];
        }
    }
    __syncthreads();

    // ---- phase 2: logits L_k = z^T Gp z  (split d1 over the 4 lanes) ----
    float L[10];
    #pragma unroll
    for (int k = 0; k < NK; ++k) {
        float zk[10];
        #pragma unroll
        for (int d = 0; d < 10; ++d) zk[d] = zrow[k * 12 + d];
        const float* g = &gp[k * 100];
        float acc = 0.f;
        for (int d1 = t; d1 < 10; d1 += 4) {
            float tmp = 0.f;
            #pragma unroll
            for (int d2 = 0; d2 < 10; ++d2) tmp += g[d1 * 10 + d2] * zk[d2];
            acc += tmp * zrow[k * 12 + d1];   // LDS read: avoids dynamic reg index
        }
        acc += __shfl_xor(acc, 1);
        acc += __shfl_xor(acc, 2);
        L[k] = acc;
    }

    // ---- softmax over k; scale z in-place -> w = c_k * z_k ----
    float m = L[0];
    #pragma unroll
    for (int k = 1; k < NK; ++k) m = fmaxf(m, L[k]);
    float e[10], s = 0.f;
    #pragma unroll
    for (int k = 0; k < NK; ++k) { e[k] = __expf(L[k] - m); s += e[k]; }
    float inv = 1.0f / s;
    #pragma unroll
    for (int k = 0; k < NK; ++k) {
        float ck = e[k] * inv;
        for (int d = t; d < 10; d += 4) zrow[k * 12 + d] *= ck;
    }
    __syncthreads();

    // ---- phase 3: out[r][b][Dslice] = sum_k Us_rk @ w_k ----
    float o[64];
    #pragma unroll
    for (int i = 0; i < 64; ++i) o[i] = 0.f;
    for (int k = 0; k < NK; ++k) {
        float wk[10];
        #pragma unroll
        for (int d = 0; d < 10; ++d) wk[d] = zrow[k * 12 + d];
        const float4* Up = (const float4*)(Us + ((size_t)(r * NK + k) * ND + t * 64) * NDL);
        #pragma unroll
        for (int i = 0; i < 32; ++i) {
            float4 u0 = Up[i*5+0];
            float4 u1 = Up[i*5+1];
            float4 u2 = Up[i*5+2];
            float4 u3 = Up[i*5+3];
            float4 u4 = Up[i*5+4];
            float oa = o[2*i], ob = o[2*i+1];
            oa += wk[0]*u0.x; oa += wk[1]*u0.y; oa += wk[2]*u0.z; oa += wk[3]*u0.w;
            oa += wk[4]*u1.x; oa += wk[5]*u1.y; oa += wk[6]*u1.z; oa += wk[7]*u1.w;
            oa += wk[8]*u2.x; oa += wk[9]*u2.y;
            ob += wk[0]*u2.z; ob += wk[1]*u2.w;
            ob += wk[2]*u3.x; ob += wk[3]*u3.y; ob += wk[4]*u3.z; ob += wk[5]*u3.w;
            ob += wk[6]*u4.x; ob += wk[7]*u4.y; ob += wk[8]*u4.z; ob += wk[9]*u4.w;
            o[2*i] = oa; o[2*i+1] = ob;
        }
    }
    float* op = out + ((size_t)r * NB + b) * ND + t * 64;
    #pragma unroll
    for (int i = 0; i < 16; ++i) {
        ((float4*)op)[i] = make_float4(o[4*i+0], o[4*i+1], o[4*i+2], o[4*i+3]);
    }
}

extern "C" void kernel_launch(void* const* d_in, const int* in_sizes, int n_in,
                              void* d_out, int out_size, void* d_ws, size_t ws_size,
                              hipStream_t stream) {
    const float* x  = (const float*)d_in[0];
    const float* Us = (const float*)d_in[1];
    float* out = (float*)d_out;
    float* Gp  = (float*)d_ws;   // 32 KB

    gram_kernel<<<dim3(NR * NK), 128, 0, stream>>>(Us, Gp);
    ksub_kernel<<<dim3(NB / 64, NR), 256, 0, stream>>>(x, Us, Gp, out);
}

// Round 2
// 133.972 us; speedup vs baseline: 5.8822x; 5.8822x over previous
//
#include <hip/hip_runtime.h>
#include <math.h>

#define NR   8
#define NK   10
#define ND   256
#define NDL  10
#define NB   4096
#define NN   100      // n = k*10+d

// LDS strides (floats)
#define XS_S 68       // xs[32][68]
#define US_S 132      // us[32][132] (n padded to 128, +4 bank stagger)
#define ZB_S 104      // zbuf[64][104]
#define WT_S 68       // wT[100][68]
#define U2_S 68       // u2[100][68]

// LDS float offsets
#define OFF_WT 0                  // 100*68      = 6800
#define OFF_SH 6800               // max(xs 2176 + us 4224, zbuf 6656, u2 6800) = 6800
#define OFF_GP 13600              // 1000
#define SMEM_F 14600              // 58400 B

__global__ __launch_bounds__(128) void gram_kernel(const float* __restrict__ Us,
                                                   float* __restrict__ Gp) {
    int rk = blockIdx.x;                       // 0..79
    const float* U = Us + (size_t)rk * ND * NDL;
    __shared__ float u[ND * NDL];              // 10 KB
    for (int i = threadIdx.x; i < ND * NDL; i += blockDim.x) u[i] = U[i];
    __syncthreads();
    int e = threadIdx.x;
    if (e < NDL * NDL) {
        int d1 = e / NDL, d2 = e % NDL;
        float acc = 0.f;
        #pragma unroll 8
        for (int Di = 0; Di < ND; ++Di)
            acc += u[Di * NDL + d1] * u[Di * NDL + d2];
        // logit = z^T (10 I - 5 G) z   (const-over-k terms cancel in softmax)
        Gp[(size_t)rk * (NDL * NDL) + e] = (d1 == d2 ? 10.0f : 0.0f) - 5.0f * acc;
    }
}

// Block: 256 threads, one (r, 64-b tile). Grid (64, 8) = 512 blocks = 2/CU.
__global__ __launch_bounds__(256, 2) void ksub_fused(const float* __restrict__ x,
                                                     const float* __restrict__ Us,
                                                     const float* __restrict__ Gp,
                                                     float* __restrict__ out) {
    __shared__ float smem[SMEM_F];
    float* wT   = smem + OFF_WT;
    float* xs   = smem + OFF_SH;          // phase-1 staging
    float* us   = smem + OFF_SH + 2176;
    float* zbuf = smem + OFF_SH;          // overlays xs/us after phase 1
    float* u2   = smem + OFF_SH;          // overlays zbuf in phase 3
    float* gp   = smem + OFF_GP;

    const int tid = threadIdx.x;
    const int r   = blockIdx.y;
    const int b0  = blockIdx.x * 64;

    // load Gp[r] (read in softmax; sync before use is covered below)
    for (int i = tid; i < NK * NDL * NDL; i += 256)
        gp[i] = Gp[(size_t)r * (NK * NDL * NDL) + i];

    // ---------------- phase 1: z[b][n] = sum_D x[b][D] * U[D][n] ----------------
    const int nt = tid & 15;   // 8 n's: [nt*8, nt*8+8)
    const int bt = tid >> 4;   // 4 b's: [bt*4, bt*4+4)

    float acc[4][8];
    #pragma unroll
    for (int j = 0; j < 4; ++j)
        #pragma unroll
        for (int i = 0; i < 8; ++i) acc[j][i] = 0.f;

    for (int c = 0; c < 8; ++c) {            // D-chunks of 32
        __syncthreads();
        // stage xs[Dl][b] (transposed X tile)
        for (int i = tid; i < 512; i += 256) {
            int b = i >> 3, f = i & 7;
            float4 v = ((const float4*)(x + (size_t)(b0 + b) * ND))[c * 8 + f];
            float* dst = xs + (f * 4) * XS_S + b;
            dst[0] = v.x; dst[XS_S] = v.y; dst[2 * XS_S] = v.z; dst[3 * XS_S] = v.w;
        }
        // stage us[Dl][k*10+d]
        for (int p = tid; p < 320; p += 256) {
            int k = p >> 5, Dl = p & 31;
            const float* g = Us + ((size_t)((r * NK + k) * ND) + c * 32 + Dl) * NDL;
            float* dst = us + Dl * US_S + k * NDL;
            #pragma unroll
            for (int d = 0; d < 10; ++d) dst[d] = g[d];
        }
        __syncthreads();
        #pragma unroll 4
        for (int Dl = 0; Dl < 32; ++Dl) {
            float4 xv = *(const float4*)(xs + Dl * XS_S + bt * 4);
            float4 ua = *(const float4*)(us + Dl * US_S + nt * 8);
            float4 ub = *(const float4*)(us + Dl * US_S + nt * 8 + 4);
            float xa[4] = {xv.x, xv.y, xv.z, xv.w};
            float uu[8] = {ua.x, ua.y, ua.z, ua.w, ub.x, ub.y, ub.z, ub.w};
            #pragma unroll
            for (int j = 0; j < 4; ++j)
                #pragma unroll
                for (int i = 0; i < 8; ++i) acc[j][i] += xa[j] * uu[i];
        }
    }

    __syncthreads();   // all xs/us reads done before zbuf overlays them
    // write z to zbuf[b][n] (only n<100; nt==12 writes n 96..99; nt>12 none)
    if (nt < 12) {
        #pragma unroll
        for (int j = 0; j < 4; ++j) {
            float* zp = zbuf + (bt * 4 + j) * ZB_S + nt * 8;
            *(float4*)(zp)     = make_float4(acc[j][0], acc[j][1], acc[j][2], acc[j][3]);
            *(float4*)(zp + 4) = make_float4(acc[j][4], acc[j][5], acc[j][6], acc[j][7]);
        }
    } else if (nt == 12) {
        #pragma unroll
        for (int j = 0; j < 4; ++j) {
            float* zp = zbuf + (bt * 4 + j) * ZB_S + 96;
            *(float4*)(zp) = make_float4(acc[j][0], acc[j][1], acc[j][2], acc[j][3]);
        }
    }
    __syncthreads();

    // ---------------- softmax over k (Gram quadform logits); write wT[n][b] = c_k*z ----
    if (tid < 64) {
        const int b_l = tid;
        const float* zrow = zbuf + b_l * ZB_S;
        float L[10];
        #pragma unroll
        for (int k = 0; k < NK; ++k) {
            float zk[10];
            #pragma unroll
            for (int d = 0; d < 10; ++d) zk[d] = zrow[k * 10 + d];
            const float* g = gp + k * 100;
            float a2 = 0.f;
            #pragma unroll
            for (int d1 = 0; d1 < 10; ++d1) {
                float t = 0.f;
                #pragma unroll
                for (int d2 = 0; d2 < 10; ++d2) t += g[d1 * 10 + d2] * zk[d2];
                a2 += t * zk[d1];
            }
            L[k] = a2;
        }
        float m = L[0];
        #pragma unroll
        for (int k = 1; k < NK; ++k) m = fmaxf(m, L[k]);
        float e[10], s = 0.f;
        #pragma unroll
        for (int k = 0; k < NK; ++k) { e[k] = __expf(L[k] - m); s += e[k]; }
        float inv = 1.0f / s;
        #pragma unroll
        for (int k = 0; k < NK; ++k) {
            float ck = e[k] * inv;
            #pragma unroll
            for (int d = 0; d < 10; ++d)
                wT[(k * 10 + d) * WT_S + b_l] = ck * zrow[k * 10 + d];
        }
    }

    // ---------------- phase 3: out[b][D] = sum_n w[b][n] * U[D][n] ----------------
    const int Dt  = tid & 15;  // 4 D's
    const int bt2 = tid >> 4;  // 4 b's

    for (int c2 = 0; c2 < 4; ++c2) {         // D-chunks of 64
        __syncthreads();                      // protects zbuf->u2 overlay + wT visibility
        for (int p = tid; p < 640; p += 256) {
            int k = p >> 6, Dl = p & 63;
            const float* g = Us + ((size_t)((r * NK + k) * ND) + c2 * 64 + Dl) * NDL;
            float* dst = u2 + (k * NDL) * U2_S + Dl;
            #pragma unroll
            for (int d = 0; d < 10; ++d) dst[d * U2_S] = g[d];
        }
        __syncthreads();
        float o[4][4];
        #pragma unroll
        for (int j = 0; j < 4; ++j)
            #pragma unroll
            for (int i = 0; i < 4; ++i) o[j][i] = 0.f;
        #pragma unroll 4
        for (int n = 0; n < NN; ++n) {
            float4 wv = *(const float4*)(wT + n * WT_S + bt2 * 4);
            float4 uv = *(const float4*)(u2 + n * U2_S + Dt * 4);
            float wa[4] = {wv.x, wv.y, wv.z, wv.w};
            float ub[4] = {uv.x, uv.y, uv.z, uv.w};
            #pragma unroll
            for (int j = 0; j < 4; ++j)
                #pragma unroll
                for (int i = 0; i < 4; ++i) o[j][i] += wa[j] * ub[i];
        }
        #pragma unroll
        for (int j = 0; j < 4; ++j) {
            float* op = out + ((size_t)r * NB + b0 + bt2 * 4 + j) * ND + c2 * 64 + Dt * 4;
            *(float4*)op = make_float4(o[j][0], o[j][1], o[j][2], o[j][3]);
        }
    }
}

extern "C" void kernel_launch(void* const* d_in, const int* in_sizes, int n_in,
                              void* d_out, int out_size, void* d_ws, size_t ws_size,
                              hipStream_t stream) {
    const float* x  = (const float*)d_in[0];
    const float* Us = (const float*)d_in[1];
    float* out = (float*)d_out;
    float* Gp  = (float*)d_ws;   // 32 KB

    gram_kernel<<<dim3(NR * NK), 128, 0, stream>>>(Us, Gp);
    ksub_fused<<<dim3(NB / 64, NR), 256, 0, stream>>>(x, Us, Gp, out);
}

// Round 3
// 133.210 us; speedup vs baseline: 5.9159x; 1.0057x over previous
//
#include <hip/hip_runtime.h>
#include <math.h>

typedef unsigned short ushort_t;
typedef unsigned int uint32_tt;
typedef __attribute__((ext_vector_type(8))) short bf16x8;
typedef __attribute__((ext_vector_type(4))) float f32x4;

#define NR   8
#define NK   10
#define ND   256
#define NDL  10
#define NB   4096
#define NN   100
#define NP   112      // phase-1 padded n (7*16)
#define NP2  128      // phase-3 padded K over n (4*32)

// ---- workspace layout (bytes) ----
#define WS_GP   0                          // fp32 Gp[8][1000] = 32,000
#define WS_XB   32768                      // bf16 x[4096][256] = 2,097,152
#define WS_U1   (32768 + 2097152)          // bf16 U1[8][112][256] = 458,752 (n-major, D contig)
#define WS_U2   (WS_U1 + 458752)           // bf16 U2[8][256][128] = 524,288 (D-major, n contig)
#define WS_NEED (WS_U2 + 524288)           // 3,112,960

__device__ __forceinline__ ushort_t f2bf(float f) {
    uint32_tt u = __float_as_uint(f);
    u = (u + 0x7FFF + ((u >> 16) & 1)) >> 16;   // RNE
    return (ushort_t)u;
}

// =====================================================================
// Prep: x->bf16, Gram (fp32), Us->bf16 in two layouts. Grid 1120 x 256.
// =====================================================================
__global__ __launch_bounds__(256) void prep_kernel(const float* __restrict__ x,
                                                   const float* __restrict__ Us,
                                                   char* __restrict__ ws) {
    __shared__ float pu[ND * NDL];
    const int bid = blockIdx.x, tid = threadIdx.x;
    if (bid < 1024) {
        // ---- x -> bf16, 1 float4 per thread ----
        ushort_t* xb = (ushort_t*)(ws + WS_XB);
        int i = bid * 256 + tid;
        float4 v = ((const float4*)x)[i];
        uint32_tt p0 = (uint32_tt)f2bf(v.x) | ((uint32_tt)f2bf(v.y) << 16);
        uint32_tt p1 = (uint32_tt)f2bf(v.z) | ((uint32_tt)f2bf(v.w) << 16);
        ((uint2*)xb)[i] = make_uint2(p0, p1);
    } else if (bid < 1104) {
        // ---- Gram: Gp = 10*I - 5*U^T U per (r,k) ----
        int rk = bid - 1024;
        float* Gp = (float*)(ws + WS_GP);
        const float* U = Us + (size_t)rk * ND * NDL;
        for (int i = tid; i < ND * NDL; i += 256) pu[i] = U[i];
        __syncthreads();
        if (tid < NDL * NDL) {
            int d1 = tid / NDL, d2 = tid % NDL;
            float acc = 0.f;
            #pragma unroll 8
            for (int Di = 0; Di < ND; ++Di)
                acc += pu[Di * NDL + d1] * pu[Di * NDL + d2];
            Gp[(size_t)rk * 100 + tid] = (d1 == d2 ? 10.0f : 0.0f) - 5.0f * acc;
        }
    } else if (bid < 1112) {
        // ---- U1[r][n][D] bf16 (zero-pad n>=100) ----
        int r = bid - 1104;
        ushort_t* u1 = (ushort_t*)(ws + WS_U1);
        for (int p = tid; p < NP * ND; p += 256) {
            int n = p >> 8, D = p & 255;
            float v = 0.f;
            if (n < NN) v = Us[((size_t)(r * NK + n / NDL) * ND + D) * NDL + (n % NDL)];
            u1[(size_t)(r * NP + n) * ND + D] = f2bf(v);
        }
    } else {
        // ---- U2[r][D][128] bf16 (zero-pad n>=100) ----
        int r = bid - 1112;
        ushort_t* u2 = (ushort_t*)(ws + WS_U2);
        for (int p = tid; p < ND * NP2; p += 256) {
            int D = p >> 7, n = p & 127;
            float v = 0.f;
            if (n < NN) v = Us[((size_t)(r * NK + n / NDL) * ND + D) * NDL + (n % NDL)];
            u2[(size_t)(r * ND + D) * NP2 + n] = f2bf(v);
        }
    }
}

// =====================================================================
// Main MFMA kernel: block = (r, 64-b tile), 256 threads, grid (64, 8).
// Phase 1: Z^T = U1 . X^T   (M=n 112, N=b 64, K=D 256)
// Phase 3: Out^T = U2 . W^T (M=D 256, N=b 64, K=n 128)
// =====================================================================
__global__ __launch_bounds__(256, 3) void ksub_mfma(const char* __restrict__ ws,
                                                    float* __restrict__ out) {
    __shared__ __align__(16) char smem[54176];
    ushort_t* xs  = (ushort_t*)smem;              // [64][256] bf16, 16B-chunk XOR-swizzled
    float*    zbuf= (float*)smem;                 // [64][100] fp32 (overlays xs)
    ushort_t* w2  = (ushort_t*)smem;              // [256][40] bf16 (overlays zbuf)
    ushort_t* w1  = (ushort_t*)(smem + 32768);    // [112][40] bf16
    ushort_t* wTb = (ushort_t*)(smem + 32768);    // [64][136] bf16 (overlays w1)
    float*    gp  = (float*)(smem + 32768 + 17408); // [1000] fp32

    const int tid  = threadIdx.x;
    const int w    = tid >> 6;      // wave = b-col tile
    const int lane = tid & 63;
    const int c    = lane & 15;
    const int q    = lane >> 4;
    const int r    = blockIdx.y;
    const int b0   = blockIdx.x * 64;
    const int bloc = w * 16 + c;    // this lane's local b (B-frag col / C col)

    const ushort_t* xb  = (const ushort_t*)(ws + WS_XB);
    const ushort_t* u1g = (const ushort_t*)(ws + WS_U1) + (size_t)r * NP * ND;
    const ushort_t* u2g = (const ushort_t*)(ws + WS_U2) + (size_t)r * ND * NP2;
    const float*    gpg = (const float*)(ws + WS_GP) + (size_t)r * 1000;

    for (int i = tid; i < 1000; i += 256) gp[i] = gpg[i];

    // ---- stage X tile [64][256] bf16, XOR-swizzle 16B chunks: pos = cc ^ (b&7) ----
    for (int p = tid; p < 2048; p += 256) {
        int b = p >> 5, cc = p & 31;
        bf16x8 v = *(const bf16x8*)(xb + (size_t)(b0 + b) * ND + cc * 8);
        *(bf16x8*)(xs + b * 256 + ((cc ^ (b & 7)) * 8)) = v;
    }

    // ---------------- phase 1 ----------------
    f32x4 acc1[7];
    #pragma unroll
    for (int t = 0; t < 7; ++t) acc1[t] = (f32x4){0.f, 0.f, 0.f, 0.f};

    for (int Dc = 0; Dc < 8; ++Dc) {
        __syncthreads();
        for (int p = tid; p < 448; p += 256) {           // stage U1 K-chunk [112][32]
            int n = p >> 2, cc = p & 3;
            bf16x8 v = *(const bf16x8*)(u1g + (size_t)n * ND + Dc * 32 + cc * 8);
            *(bf16x8*)(w1 + n * 40 + cc * 8) = v;
        }
        __syncthreads();
        // B-frag: X^T[k=D][b]: lane j-th elem = x[bloc][Dc*32+q*8+j]
        bf16x8 bfr = *(const bf16x8*)(xs + bloc * 256 + (((Dc * 4 + q) ^ (bloc & 7)) * 8));
        #pragma unroll
        for (int t = 0; t < 7; ++t) {
            bf16x8 afr = *(const bf16x8*)(w1 + (t * 16 + c) * 40 + q * 8);
            acc1[t] = __builtin_amdgcn_mfma_f32_16x16x32_bf16(afr, bfr, acc1[t], 0, 0, 0);
        }
    }

    __syncthreads();                 // all xs reads done; zbuf overlays xs
    // ---- dump Z^T C-frags: row n = t*16+q*4+reg, col b = bloc ----
    #pragma unroll
    for (int t = 0; t < 7; ++t) {
        #pragma unroll
        for (int rg = 0; rg < 4; ++rg) {
            int n = t * 16 + q * 4 + rg;
            if (n < NN) zbuf[bloc * 100 + n] = acc1[t][rg];
        }
    }
    __syncthreads();                 // zbuf ready; w1 dead (wTb may be written)

    // ---------------- softmax (all 256 threads: b = tid>>2, k split on 4 lanes) ----
    {
        const int b  = tid >> 2;
        const int kq = tid & 3;
        const float* zr = zbuf + b * 100;
        float zk[3][10], L[3];
        #pragma unroll
        for (int j = 0; j < 3; ++j) {
            int k = kq + 4 * j;
            L[j] = -1e30f;
            if (k < NK) {
                #pragma unroll
                for (int d = 0; d < 10; ++d) zk[j][d] = zr[k * 10 + d];
                const float* g = gp + k * 100;
                float acc = 0.f;
                #pragma unroll
                for (int d1 = 0; d1 < 10; ++d1) {
                    float t2 = 0.f;
                    #pragma unroll
                    for (int d2 = 0; d2 < 10; ++d2) t2 += g[d1 * 10 + d2] * zk[j][d2];
                    acc += t2 * zk[j][d1];
                }
                L[j] = acc;
            }
        }
        float m = fmaxf(fmaxf(L[0], L[1]), L[2]);
        m = fmaxf(m, __shfl_xor(m, 1));
        m = fmaxf(m, __shfl_xor(m, 2));
        float e[3], s = 0.f;
        #pragma unroll
        for (int j = 0; j < 3; ++j) {
            e[j] = (kq + 4 * j < NK) ? __expf(L[j] - m) : 0.f;
            s += e[j];
        }
        s += __shfl_xor(s, 1);
        s += __shfl_xor(s, 2);
        float inv = 1.0f / s;
        #pragma unroll
        for (int j = 0; j < 3; ++j) {
            int k = kq + 4 * j;
            if (k < NK) {
                float ck = e[j] * inv;
                #pragma unroll
                for (int d = 0; d < 10; ++d)
                    wTb[b * 136 + k * 10 + d] = f2bf(ck * zk[j][d]);
            }
        }
    }
    // zero-pad wTb n in [100,128)
    for (int i = tid; i < 64 * 28; i += 256) {
        int b = i / 28, n = 100 + i % 28;
        wTb[b * 136 + n] = 0;
    }
    __syncthreads();

    // ---------------- phase 3 ----------------
    f32x4 acc3[16];
    #pragma unroll
    for (int t = 0; t < 16; ++t) acc3[t] = (f32x4){0.f, 0.f, 0.f, 0.f};

    for (int nc = 0; nc < 4; ++nc) {
        __syncthreads();
        for (int p = tid; p < 1024; p += 256) {          // stage U2 K-chunk [256][32]
            int D = p >> 2, cc = p & 3;
            bf16x8 v = *(const bf16x8*)(u2g + (size_t)D * NP2 + nc * 32 + cc * 8);
            *(bf16x8*)(w2 + D * 40 + cc * 8) = v;
        }
        __syncthreads();
        // B-frag: W^T[k=n][b]: lane j-th elem = wTb[bloc][nc*32+q*8+j]
        bf16x8 bfr = *(const bf16x8*)(wTb + bloc * 136 + nc * 32 + q * 8);
        #pragma unroll
        for (int dt = 0; dt < 16; ++dt) {
            bf16x8 afr = *(const bf16x8*)(w2 + (dt * 16 + c) * 40 + q * 8);
            acc3[dt] = __builtin_amdgcn_mfma_f32_16x16x32_bf16(afr, bfr, acc3[dt], 0, 0, 0);
        }
    }

    // ---- store Out^T C-frags: lane holds 4 consecutive D for col b = bloc ----
    size_t obase = ((size_t)r * NB + b0 + bloc) * ND;
    #pragma unroll
    for (int dt = 0; dt < 16; ++dt) {
        *(f32x4*)(out + obase + dt * 16 + q * 4) = acc3[dt];
    }
}

// =====================================================================
// Fallback (round-2 verified path) if ws is too small for bf16 buffers
// =====================================================================
#define XS_S 68
#define US_S 132
#define ZB_S 104
#define WT_S 68
#define U2_S 68
#define OFF_WT 0
#define OFF_SH 6800
#define OFF_GP 13600
#define SMEM_F 14600

__global__ __launch_bounds__(128) void gram_kernel(const float* __restrict__ Us,
                                                   float* __restrict__ Gp) {
    int rk = blockIdx.x;
    const float* U = Us + (size_t)rk * ND * NDL;
    __shared__ float u[ND * NDL];
    for (int i = threadIdx.x; i < ND * NDL; i += blockDim.x) u[i] = U[i];
    __syncthreads();
    int e = threadIdx.x;
    if (e < NDL * NDL) {
        int d1 = e / NDL, d2 = e % NDL;
        float acc = 0.f;
        #pragma unroll 8
        for (int Di = 0; Di < ND; ++Di)
            acc += u[Di * NDL + d1] * u[Di * NDL + d2];
        Gp[(size_t)rk * (NDL * NDL) + e] = (d1 == d2 ? 10.0f : 0.0f) - 5.0f * acc;
    }
}

__global__ __launch_bounds__(256, 2) void ksub_fused(const float* __restrict__ x,
                                                     const float* __restrict__ Us,
                                                     const float* __restrict__ Gp,
                                                     float* __restrict__ out) {
    __shared__ float smemf[SMEM_F];
    float* wT   = smemf + OFF_WT;
    float* xsf  = smemf + OFF_SH;
    float* usf  = smemf + OFF_SH + 2176;
    float* zbuf = smemf + OFF_SH;
    float* u2   = smemf + OFF_SH;
    float* gp   = smemf + OFF_GP;

    const int tid = threadIdx.x;
    const int r   = blockIdx.y;
    const int b0  = blockIdx.x * 64;

    for (int i = tid; i < NK * NDL * NDL; i += 256)
        gp[i] = Gp[(size_t)r * (NK * NDL * NDL) + i];

    const int nt = tid & 15;
    const int bt = tid >> 4;
    float acc[4][8];
    #pragma unroll
    for (int j = 0; j < 4; ++j)
        #pragma unroll
        for (int i = 0; i < 8; ++i) acc[j][i] = 0.f;

    for (int cch = 0; cch < 8; ++cch) {
        __syncthreads();
        for (int i = tid; i < 512; i += 256) {
            int b = i >> 3, f = i & 7;
            float4 v = ((const float4*)(x + (size_t)(b0 + b) * ND))[cch * 8 + f];
            float* dst = xsf + (f * 4) * XS_S + b;
            dst[0] = v.x; dst[XS_S] = v.y; dst[2 * XS_S] = v.z; dst[3 * XS_S] = v.w;
        }
        for (int p = tid; p < 320; p += 256) {
            int k = p >> 5, Dl = p & 31;
            const float* g = Us + ((size_t)((r * NK + k) * ND) + cch * 32 + Dl) * NDL;
            float* dst = usf + Dl * US_S + k * NDL;
            #pragma unroll
            for (int d = 0; d < 10; ++d) dst[d] = g[d];
        }
        __syncthreads();
        #pragma unroll 4
        for (int Dl = 0; Dl < 32; ++Dl) {
            float4 xv = *(const float4*)(xsf + Dl * XS_S + bt * 4);
            float4 ua = *(const float4*)(usf + Dl * US_S + nt * 8);
            float4 ub = *(const float4*)(usf + Dl * US_S + nt * 8 + 4);
            float xa[4] = {xv.x, xv.y, xv.z, xv.w};
            float uu[8] = {ua.x, ua.y, ua.z, ua.w, ub.x, ub.y, ub.z, ub.w};
            #pragma unroll
            for (int j = 0; j < 4; ++j)
                #pragma unroll
                for (int i = 0; i < 8; ++i) acc[j][i] += xa[j] * uu[i];
        }
    }
    __syncthreads();
    if (nt < 12) {
        #pragma unroll
        for (int j = 0; j < 4; ++j) {
            float* zp = zbuf + (bt * 4 + j) * ZB_S + nt * 8;
            *(float4*)(zp)     = make_float4(acc[j][0], acc[j][1], acc[j][2], acc[j][3]);
            *(float4*)(zp + 4) = make_float4(acc[j][4], acc[j][5], acc[j][6], acc[j][7]);
        }
    } else if (nt == 12) {
        #pragma unroll
        for (int j = 0; j < 4; ++j) {
            float* zp = zbuf + (bt * 4 + j) * ZB_S + 96;
            *(float4*)(zp) = make_float4(acc[j][0], acc[j][1], acc[j][2], acc[j][3]);
        }
    }
    __syncthreads();
    if (tid < 64) {
        const int b_l = tid;
        const float* zrow = zbuf + b_l * ZB_S;
        float L[10];
        #pragma unroll
        for (int k = 0; k < NK; ++k) {
            float zk[10];
            #pragma unroll
            for (int d = 0; d < 10; ++d) zk[d] = zrow[k * 10 + d];
            const float* g = gp + k * 100;
            float a2 = 0.f;
            #pragma unroll
            for (int d1 = 0; d1 < 10; ++d1) {
                float t = 0.f;
                #pragma unroll
                for (int d2 = 0; d2 < 10; ++d2) t += g[d1 * 10 + d2] * zk[d2];
                a2 += t * zk[d1];
            }
            L[k] = a2;
        }
        float m = L[0];
        #pragma unroll
        for (int k = 1; k < NK; ++k) m = fmaxf(m, L[k]);
        float e[10], s = 0.f;
        #pragma unroll
        for (int k = 0; k < NK; ++k) { e[k] = __expf(L[k] - m); s += e[k]; }
        float inv = 1.0f / s;
        #pragma unroll
        for (int k = 0; k < NK; ++k) {
            float ck = e[k] * inv;
            #pragma unroll
            for (int d = 0; d < 10; ++d)
                wT[(k * 10 + d) * WT_S + b_l] = ck * zrow[k * 10 + d];
        }
    }
    const int Dt  = tid & 15;
    const int bt2 = tid >> 4;
    for (int c2 = 0; c2 < 4; ++c2) {
        __syncthreads();
        for (int p = tid; p < 640; p += 256) {
            int k = p >> 6, Dl = p & 63;
            const float* g = Us + ((size_t)((r * NK + k) * ND) + c2 * 64 + Dl) * NDL;
            float* dst = u2 + (k * NDL) * U2_S + Dl;
            #pragma unroll
            for (int d = 0; d < 10; ++d) dst[d * U2_S] = g[d];
        }
        __syncthreads();
        float o[4][4];
        #pragma unroll
        for (int j = 0; j < 4; ++j)
            #pragma unroll
            for (int i = 0; i < 4; ++i) o[j][i] = 0.f;
        #pragma unroll 4
        for (int n = 0; n < NN; ++n) {
            float4 wv = *(const float4*)(wT + n * WT_S + bt2 * 4);
            float4 uv = *(const float4*)(u2 + n * U2_S + Dt * 4);
            float wa[4] = {wv.x, wv.y, wv.z, wv.w};
            float ub[4] = {uv.x, uv.y, uv.z, uv.w};
            #pragma unroll
            for (int j = 0; j < 4; ++j)
                #pragma unroll
                for (int i = 0; i < 4; ++i) o[j][i] += wa[j] * ub[i];
        }
        #pragma unroll
        for (int j = 0; j < 4; ++j) {
            float* op = out + ((size_t)r * NB + b0 + bt2 * 4 + j) * ND + c2 * 64 + Dt * 4;
            *(float4*)op = make_float4(o[j][0], o[j][1], o[j][2], o[j][3]);
        }
    }
}

extern "C" void kernel_launch(void* const* d_in, const int* in_sizes, int n_in,
                              void* d_out, int out_size, void* d_ws, size_t ws_size,
                              hipStream_t stream) {
    const float* x  = (const float*)d_in[0];
    const float* Us = (const float*)d_in[1];
    float* out = (float*)d_out;

    if (ws_size >= (size_t)WS_NEED) {
        prep_kernel<<<dim3(1120), 256, 0, stream>>>(x, Us, (char*)d_ws);
        ksub_mfma<<<dim3(NB / 64, NR), 256, 0, stream>>>((const char*)d_ws, out);
    } else {
        gram_kernel<<<dim3(NR * NK), 128, 0, stream>>>(Us, (float*)d_ws);
        ksub_fused<<<dim3(NB / 64, NR), 256, 0, stream>>>(x, Us, (float*)d_ws, out);
    }
}

// Round 4
// 129.430 us; speedup vs baseline: 6.0887x; 1.0292x over previous
//
#include <hip/hip_runtime.h>
#include <math.h>

typedef unsigned short ushort_t;
typedef unsigned int uint32_tt;
typedef __attribute__((ext_vector_type(8))) short bf16x8;
typedef __attribute__((ext_vector_type(4))) float f32x4;

#define NR   8
#define NK   10
#define ND   256
#define NDL  10
#define NB   4096
#define NN   100
#define NP   112      // phase-1 padded n (7*16)
#define NP2  128      // phase-3 padded K over n (4*32)

// ---- workspace layout (bytes) ----
#define WS_GP   0                          // fp32 Gp[8][1000] = 32,000
#define WS_XB   32768                      // bf16 x[4096][256] = 2,097,152
#define WS_U1   (32768 + 2097152)          // bf16 U1[8][112][256] (n-major, D contig)
#define WS_U2   (WS_U1 + 458752)           // bf16 U2[8][256][128] (D-major, n contig)
#define WS_NEED (WS_U2 + 524288)           // 3,112,960

__device__ __forceinline__ ushort_t f2bf(float f) {
    uint32_tt u = __float_as_uint(f);
    u = (u + 0x7FFF + ((u >> 16) & 1)) >> 16;   // RNE
    return (ushort_t)u;
}

// =====================================================================
// Prep: bid<1024: x->bf16 (coalesced). bid>=1024: one block per (r,k):
// load Us[rk] 10KB coalesced -> LDS, emit Gram + U1 slice + U2 slice
// with coalesced writes. Grid 1104 x 256.
// =====================================================================
__global__ __launch_bounds__(256) void prep_kernel(const float* __restrict__ x,
                                                   const float* __restrict__ Us,
                                                   char* __restrict__ ws) {
    __shared__ float lu[ND * NDL];     // 10 KB, layout [D][d] stride 10
    const int bid = blockIdx.x, tid = threadIdx.x;

    if (bid < 1024) {
        ushort_t* xb = (ushort_t*)(ws + WS_XB);
        int i = bid * 256 + tid;
        float4 v = ((const float4*)x)[i];
        uint32_tt p0 = (uint32_tt)f2bf(v.x) | ((uint32_tt)f2bf(v.y) << 16);
        uint32_tt p1 = (uint32_tt)f2bf(v.z) | ((uint32_tt)f2bf(v.w) << 16);
        ((uint2*)xb)[i] = make_uint2(p0, p1);
        return;
    }

    const int rk = bid - 1024;               // 0..79
    const int r  = rk / NK, k = rk - r * NK;
    const float* U = Us + (size_t)rk * ND * NDL;
    for (int i = tid; i < 640; i += 256)
        ((float4*)lu)[i] = ((const float4*)U)[i];
    __syncthreads();

    // ---- Gram: Gp = 10*I - 5*U^T U ----
    float* Gp = (float*)(ws + WS_GP);
    if (tid < NDL * NDL) {
        int d1 = tid / NDL, d2 = tid - d1 * NDL;
        float acc = 0.f;
        #pragma unroll 8
        for (int Di = 0; Di < ND; ++Di)
            acc += lu[Di * NDL + d1] * lu[Di * NDL + d2];
        Gp[(size_t)rk * 100 + tid] = (d1 == d2 ? 10.0f : 0.0f) - 5.0f * acc;
    }

    // ---- U1[r][k*10+d][D] bf16, coalesced in D ----
    ushort_t* u1 = (ushort_t*)(ws + WS_U1);
    for (int p = tid; p < ND * NDL; p += 256) {
        int d = p >> 8, D = p & 255;
        u1[((size_t)r * NP + k * NDL + d) * ND + D] = f2bf(lu[D * NDL + d]);
    }

    // ---- U2[r][D][k*10..k*10+10) bf16, one D-row per thread, packed uints ----
    ushort_t* u2 = (ushort_t*)(ws + WS_U2);
    {
        int D = tid;
        uint32_tt* dst = (uint32_tt*)(u2 + ((size_t)r * ND + D) * NP2 + k * NDL);
        const float* src = lu + D * NDL;
        #pragma unroll
        for (int j = 0; j < 5; ++j)
            dst[j] = (uint32_tt)f2bf(src[2 * j]) | ((uint32_tt)f2bf(src[2 * j + 1]) << 16);
    }

    // ---- zero pads (k==9 block only) ----
    if (k == NK - 1) {
        for (int p = tid; p < 12 * ND; p += 256) {
            int n = p >> 8, D = p & 255;
            u1[((size_t)r * NP + 100 + n) * ND + D] = 0;
        }
        uint32_tt* u2u = (uint32_tt*)u2;
        #pragma unroll
        for (int j = 0; j < 14; ++j)
            u2u[((size_t)r * ND + tid) * (NP2 / 2) + 50 + j] = 0;
    }
}

// =====================================================================
// Main MFMA kernel: block = (r, 64-b tile), 256 threads, grid (64, 8).
// All A/B fragments are DIRECT global loads (16B contiguous per lane) —
// no LDS staging. LDS only for z / wTb (overlay) / gp.
// Phase 1: Z^T = U1 . X^T   (M=n 112, N=b 64, K=D 256)
// Phase 3: Out^T = U2 . W^T (M=D 256, N=b 64, K=n 128)
// =====================================================================
__global__ __launch_bounds__(256, 4) void ksub_mfma2(const char* __restrict__ ws,
                                                     float* __restrict__ out) {
    __shared__ __align__(16) char smem[29600];
    float*    zbuf = (float*)smem;               // [64][100] fp32
    ushort_t* wTb  = (ushort_t*)smem;            // [64][136] bf16 (overlays zbuf)
    float*    gp   = (float*)(smem + 25600);     // [1000] fp32

    const int tid  = threadIdx.x;
    const int w    = tid >> 6;
    const int lane = tid & 63;
    const int c    = lane & 15;
    const int q    = lane >> 4;
    const int r    = blockIdx.y;
    const int b0   = blockIdx.x * 64;
    const int bloc = w * 16 + c;

    const ushort_t* xb  = (const ushort_t*)(ws + WS_XB) + (size_t)(b0 + bloc) * ND + q * 8;
    const ushort_t* u1g = (const ushort_t*)(ws + WS_U1) + (size_t)r * NP * ND + c * ND + q * 8;
    const ushort_t* u2g = (const ushort_t*)(ws + WS_U2) + (size_t)r * ND * NP2 + c * NP2 + q * 8;
    const float*    gpg = (const float*)(ws + WS_GP) + (size_t)r * 1000;

    for (int i = tid; i < 1000; i += 256) gp[i] = gpg[i];

    // ---------------- phase 1: direct-global fragments ----------------
    bf16x8 xfr[8];
    #pragma unroll
    for (int Dc = 0; Dc < 8; ++Dc)
        xfr[Dc] = *(const bf16x8*)(xb + Dc * 32);

    f32x4 acc1[7];
    #pragma unroll
    for (int t = 0; t < 7; ++t) acc1[t] = (f32x4){0.f, 0.f, 0.f, 0.f};

    #pragma unroll
    for (int Dc = 0; Dc < 8; ++Dc) {
        bf16x8 a[7];
        #pragma unroll
        for (int t = 0; t < 7; ++t)
            a[t] = *(const bf16x8*)(u1g + t * 16 * ND + Dc * 32);
        #pragma unroll
        for (int t = 0; t < 7; ++t)
            acc1[t] = __builtin_amdgcn_mfma_f32_16x16x32_bf16(a[t], xfr[Dc], acc1[t], 0, 0, 0);
    }

    // ---- dump Z^T C-frags: row n = t*16+q*4+reg, col b = bloc ----
    #pragma unroll
    for (int t = 0; t < 7; ++t) {
        #pragma unroll
        for (int rg = 0; rg < 4; ++rg) {
            int n = t * 16 + q * 4 + rg;
            if (n < NN) zbuf[bloc * 100 + n] = acc1[t][rg];
        }
    }
    __syncthreads();

    // ---------------- softmax: b = tid>>2, k split on 4 lanes ----------------
    const int bsm = tid >> 2;
    const int kq  = tid & 3;
    float zk[3][10], ee[3];
    {
        const float* zr = zbuf + bsm * 100;
        float L[3];
        #pragma unroll
        for (int j = 0; j < 3; ++j) {
            int k = kq + 4 * j;
            L[j] = -1e30f;
            if (k < NK) {
                #pragma unroll
                for (int d = 0; d < 10; ++d) zk[j][d] = zr[k * 10 + d];
                const float* g = gp + k * 100;
                float acc = 0.f;
                #pragma unroll
                for (int d1 = 0; d1 < 10; ++d1) {
                    float t2 = 0.f;
                    #pragma unroll
                    for (int d2 = 0; d2 < 10; ++d2) t2 += g[d1 * 10 + d2] * zk[j][d2];
                    acc += t2 * zk[j][d1];
                }
                L[j] = acc;
            }
        }
        float m = fmaxf(fmaxf(L[0], L[1]), L[2]);
        m = fmaxf(m, __shfl_xor(m, 1));
        m = fmaxf(m, __shfl_xor(m, 2));
        float s = 0.f;
        #pragma unroll
        for (int j = 0; j < 3; ++j) {
            ee[j] = (kq + 4 * j < NK) ? __expf(L[j] - m) : 0.f;
            s += ee[j];
        }
        s += __shfl_xor(s, 1);
        s += __shfl_xor(s, 2);
        float inv = 1.0f / s;
        #pragma unroll
        for (int j = 0; j < 3; ++j) ee[j] *= inv;
    }
    __syncthreads();               // all zbuf reads done; wTb overlay safe

    #pragma unroll
    for (int j = 0; j < 3; ++j) {
        int k = kq + 4 * j;
        if (k < NK) {
            #pragma unroll
            for (int d = 0; d < 10; ++d)
                wTb[bsm * 136 + k * 10 + d] = f2bf(ee[j] * zk[j][d]);
        }
    }
    // zero-pad wTb n in [100,128): 14 uints per row
    for (int i = tid; i < 1024; i += 256) {
        int jj = i & 15;
        if (jj < 14) ((uint32_tt*)wTb)[(i >> 4) * 68 + 50 + jj] = 0;
    }
    __syncthreads();

    // ---------------- phase 3: direct-global A, LDS B ----------------
    f32x4 acc3[16];
    #pragma unroll
    for (int t = 0; t < 16; ++t) acc3[t] = (f32x4){0.f, 0.f, 0.f, 0.f};

    #pragma unroll
    for (int nc = 0; nc < 4; ++nc) {
        bf16x8 bfr = *(const bf16x8*)(wTb + bloc * 136 + nc * 32 + q * 8);
        #pragma unroll
        for (int h = 0; h < 2; ++h) {
            bf16x8 a[8];
            #pragma unroll
            for (int j = 0; j < 8; ++j)
                a[j] = *(const bf16x8*)(u2g + (h * 8 + j) * 16 * NP2 + nc * 32);
            #pragma unroll
            for (int j = 0; j < 8; ++j)
                acc3[h * 8 + j] = __builtin_amdgcn_mfma_f32_16x16x32_bf16(a[j], bfr, acc3[h * 8 + j], 0, 0, 0);
        }
    }

    // ---- store Out^T C-frags: lane holds 4 consecutive D for row b = bloc ----
    size_t obase = ((size_t)r * NB + b0 + bloc) * ND;
    #pragma unroll
    for (int dt = 0; dt < 16; ++dt)
        *(f32x4*)(out + obase + dt * 16 + q * 4) = acc3[dt];
}

// =====================================================================
// Fallback (round-2 verified path) if ws is too small for bf16 buffers
// =====================================================================
#define XS_S 68
#define US_S 132
#define ZB_S 104
#define WT_S 68
#define U2_S 68
#define OFF_WT 0
#define OFF_SH 6800
#define OFF_GP 13600
#define SMEM_F 14600

__global__ __launch_bounds__(128) void gram_kernel(const float* __restrict__ Us,
                                                   float* __restrict__ Gp) {
    int rk = blockIdx.x;
    const float* U = Us + (size_t)rk * ND * NDL;
    __shared__ float u[ND * NDL];
    for (int i = threadIdx.x; i < ND * NDL; i += blockDim.x) u[i] = U[i];
    __syncthreads();
    int e = threadIdx.x;
    if (e < NDL * NDL) {
        int d1 = e / NDL, d2 = e % NDL;
        float acc = 0.f;
        #pragma unroll 8
        for (int Di = 0; Di < ND; ++Di)
            acc += u[Di * NDL + d1] * u[Di * NDL + d2];
        Gp[(size_t)rk * (NDL * NDL) + e] = (d1 == d2 ? 10.0f : 0.0f) - 5.0f * acc;
    }
}

__global__ __launch_bounds__(256, 2) void ksub_fused(const float* __restrict__ x,
                                                     const float* __restrict__ Us,
                                                     const float* __restrict__ Gp,
                                                     float* __restrict__ out) {
    __shared__ float smemf[SMEM_F];
    float* wT   = smemf + OFF_WT;
    float* xsf  = smemf + OFF_SH;
    float* usf  = smemf + OFF_SH + 2176;
    float* zbuf = smemf + OFF_SH;
    float* u2   = smemf + OFF_SH;
    float* gp   = smemf + OFF_GP;

    const int tid = threadIdx.x;
    const int r   = blockIdx.y;
    const int b0  = blockIdx.x * 64;

    for (int i = tid; i < NK * NDL * NDL; i += 256)
        gp[i] = Gp[(size_t)r * (NK * NDL * NDL) + i];

    const int nt = tid & 15;
    const int bt = tid >> 4;
    float acc[4][8];
    #pragma unroll
    for (int j = 0; j < 4; ++j)
        #pragma unroll
        for (int i = 0; i < 8; ++i) acc[j][i] = 0.f;

    for (int cch = 0; cch < 8; ++cch) {
        __syncthreads();
        for (int i = tid; i < 512; i += 256) {
            int b = i >> 3, f = i & 7;
            float4 v = ((const float4*)(x + (size_t)(b0 + b) * ND))[cch * 8 + f];
            float* dst = xsf + (f * 4) * XS_S + b;
            dst[0] = v.x; dst[XS_S] = v.y; dst[2 * XS_S] = v.z; dst[3 * XS_S] = v.w;
        }
        for (int p = tid; p < 320; p += 256) {
            int k = p >> 5, Dl = p & 31;
            const float* g = Us + ((size_t)((r * NK + k) * ND) + cch * 32 + Dl) * NDL;
            float* dst = usf + Dl * US_S + k * NDL;
            #pragma unroll
            for (int d = 0; d < 10; ++d) dst[d] = g[d];
        }
        __syncthreads();
        #pragma unroll 4
        for (int Dl = 0; Dl < 32; ++Dl) {
            float4 xv = *(const float4*)(xsf + Dl * XS_S + bt * 4);
            float4 ua = *(const float4*)(usf + Dl * US_S + nt * 8);
            float4 ub = *(const float4*)(usf + Dl * US_S + nt * 8 + 4);
            float xa[4] = {xv.x, xv.y, xv.z, xv.w};
            float uu[8] = {ua.x, ua.y, ua.z, ua.w, ub.x, ub.y, ub.z, ub.w};
            #pragma unroll
            for (int j = 0; j < 4; ++j)
                #pragma unroll
                for (int i = 0; i < 8; ++i) acc[j][i] += xa[j] * uu[i];
        }
    }
    __syncthreads();
    if (nt < 12) {
        #pragma unroll
        for (int j = 0; j < 4; ++j) {
            float* zp = zbuf + (bt * 4 + j) * ZB_S + nt * 8;
            *(float4*)(zp)     = make_float4(acc[j][0], acc[j][1], acc[j][2], acc[j][3]);
            *(float4*)(zp + 4) = make_float4(acc[j][4], acc[j][5], acc[j][6], acc[j][7]);
        }
    } else if (nt == 12) {
        #pragma unroll
        for (int j = 0; j < 4; ++j) {
            float* zp = zbuf + (bt * 4 + j) * ZB_S + 96;
            *(float4*)(zp) = make_float4(acc[j][0], acc[j][1], acc[j][2], acc[j][3]);
        }
    }
    __syncthreads();
    if (tid < 64) {
        const int b_l = tid;
        const float* zrow = zbuf + b_l * ZB_S;
        float L[10];
        #pragma unroll
        for (int k = 0; k < NK; ++k) {
            float zk[10];
            #pragma unroll
            for (int d = 0; d < 10; ++d) zk[d] = zrow[k * 10 + d];
            const float* g = gp + k * 100;
            float a2 = 0.f;
            #pragma unroll
            for (int d1 = 0; d1 < 10; ++d1) {
                float t = 0.f;
                #pragma unroll
                for (int d2 = 0; d2 < 10; ++d2) t += g[d1 * 10 + d2] * zk[d2];
                a2 += t * zk[d1];
            }
            L[k] = a2;
        }
        float m = L[0];
        #pragma unroll
        for (int k = 1; k < NK; ++k) m = fmaxf(m, L[k]);
        float e[10], s = 0.f;
        #pragma unroll
        for (int k = 0; k < NK; ++k) { e[k] = __expf(L[k] - m); s += e[k]; }
        float inv = 1.0f / s;
        #pragma unroll
        for (int k = 0; k < NK; ++k) {
            float ck = e[k] * inv;
            #pragma unroll
            for (int d = 0; d < 10; ++d)
                wT[(k * 10 + d) * WT_S + b_l] = ck * zrow[k * 10 + d];
        }
    }
    const int Dt  = tid & 15;
    const int bt2 = tid >> 4;
    for (int c2 = 0; c2 < 4; ++c2) {
        __syncthreads();
        for (int p = tid; p < 640; p += 256) {
            int k = p >> 6, Dl = p & 63;
            const float* g = Us + ((size_t)((r * NK + k) * ND) + c2 * 64 + Dl) * NDL;
            float* dst = u2 + (k * NDL) * U2_S + Dl;
            #pragma unroll
            for (int d = 0; d < 10; ++d) dst[d * U2_S] = g[d];
        }
        __syncthreads();
        float o[4][4];
        #pragma unroll
        for (int j = 0; j < 4; ++j)
            #pragma unroll
            for (int i = 0; i < 4; ++i) o[j][i] = 0.f;
        #pragma unroll 4
        for (int n = 0; n < NN; ++n) {
            float4 wv = *(const float4*)(wT + n * WT_S + bt2 * 4);
            float4 uv = *(const float4*)(u2 + n * U2_S + Dt * 4);
            float wa[4] = {wv.x, wv.y, wv.z, wv.w};
            float ub[4] = {uv.x, uv.y, uv.z, uv.w};
            #pragma unroll
            for (int j = 0; j < 4; ++j)
                #pragma unroll
                for (int i = 0; i < 4; ++i) o[j][i] += wa[j] * ub[i];
        }
        #pragma unroll
        for (int j = 0; j < 4; ++j) {
            float* op = out + ((size_t)r * NB + b0 + bt2 * 4 + j) * ND + c2 * 64 + Dt * 4;
            *(float4*)op = make_float4(o[j][0], o[j][1], o[j][2], o[j][3]);
        }
    }
}

extern "C" void kernel_launch(void* const* d_in, const int* in_sizes, int n_in,
                              void* d_out, int out_size, void* d_ws, size_t ws_size,
                              hipStream_t stream) {
    const float* x  = (const float*)d_in[0];
    const float* Us = (const float*)d_in[1];
    float* out = (float*)d_out;

    if (ws_size >= (size_t)WS_NEED) {
        prep_kernel<<<dim3(1104), 256, 0, stream>>>(x, Us, (char*)d_ws);
        ksub_mfma2<<<dim3(NB / 64, NR), 256, 0, stream>>>((const char*)d_ws, out);
    } else {
        gram_kernel<<<dim3(NR * NK), 128, 0, stream>>>(Us, (float*)d_ws);
        ksub_fused<<<dim3(NB / 64, NR), 256, 0, stream>>>(x, Us, (float*)d_ws, out);
    }
}

// Round 5
// 108.184 us; speedup vs baseline: 7.2844x; 1.1964x over previous
//
#include <hip/hip_runtime.h>
#include <math.h>

typedef unsigned short ushort_t;
typedef unsigned int uint32_tt;
typedef __attribute__((ext_vector_type(8))) short bf16x8;
typedef __attribute__((ext_vector_type(4))) float f32x4;

#define NR   8
#define NK   10
#define ND   256
#define NDL  10
#define NB   4096
#define NN   100
#define NP   112      // phase-1 padded n (7*16)
#define NP2  128      // phase-3 padded K over n (4*32)

// ---- workspace layout (bytes) ----
#define WS_GP   0                          // fp32 Gp[8][1000] = 32,000
#define WS_XB   32768                      // bf16 x[4096][256] = 2,097,152
#define WS_U1   (32768 + 2097152)          // bf16 U1[8][112][256] (n-major, D contig)
#define WS_U2   (WS_U1 + 458752)           // bf16 U2[8][256][128] (D-major, n contig)
#define WS_NEED (WS_U2 + 524288)           // 3,112,960

__device__ __forceinline__ ushort_t f2bf(float f) {
    uint32_tt u = __float_as_uint(f);
    u = (u + 0x7FFF + ((u >> 16) & 1)) >> 16;   // RNE
    return (ushort_t)u;
}

// =====================================================================
// Prep: bid<1024: x->bf16 (coalesced). bid>=1024: one block per (r,k):
// load Us[rk] 10KB coalesced -> LDS, emit Gram + U1 slice + U2 slice.
// =====================================================================
__global__ __launch_bounds__(256) void prep_kernel(const float* __restrict__ x,
                                                   const float* __restrict__ Us,
                                                   char* __restrict__ ws) {
    __shared__ float lu[ND * NDL];     // 10 KB, layout [D][d] stride 10
    const int bid = blockIdx.x, tid = threadIdx.x;

    if (bid < 1024) {
        ushort_t* xb = (ushort_t*)(ws + WS_XB);
        int i = bid * 256 + tid;
        float4 v = ((const float4*)x)[i];
        uint32_tt p0 = (uint32_tt)f2bf(v.x) | ((uint32_tt)f2bf(v.y) << 16);
        uint32_tt p1 = (uint32_tt)f2bf(v.z) | ((uint32_tt)f2bf(v.w) << 16);
        ((uint2*)xb)[i] = make_uint2(p0, p1);
        return;
    }

    const int rk = bid - 1024;               // 0..79
    const int r  = rk / NK, k = rk - r * NK;
    const float* U = Us + (size_t)rk * ND * NDL;
    for (int i = tid; i < 640; i += 256)
        ((float4*)lu)[i] = ((const float4*)U)[i];
    __syncthreads();

    // ---- Gram: Gp = 10*I - 5*U^T U (fp32 -> logits stay accurate) ----
    float* Gp = (float*)(ws + WS_GP);
    if (tid < NDL * NDL) {
        int d1 = tid / NDL, d2 = tid - d1 * NDL;
        float acc = 0.f;
        #pragma unroll 8
        for (int Di = 0; Di < ND; ++Di)
            acc += lu[Di * NDL + d1] * lu[Di * NDL + d2];
        Gp[(size_t)rk * 100 + tid] = (d1 == d2 ? 10.0f : 0.0f) - 5.0f * acc;
    }

    // ---- U1[r][k*10+d][D] bf16, coalesced in D ----
    ushort_t* u1 = (ushort_t*)(ws + WS_U1);
    for (int p = tid; p < ND * NDL; p += 256) {
        int d = p >> 8, D = p & 255;
        u1[((size_t)r * NP + k * NDL + d) * ND + D] = f2bf(lu[D * NDL + d]);
    }

    // ---- U2[r][D][k*10..k*10+10) bf16, one D-row per thread ----
    ushort_t* u2 = (ushort_t*)(ws + WS_U2);
    {
        int D = tid;
        uint32_tt* dst = (uint32_tt*)(u2 + ((size_t)r * ND + D) * NP2 + k * NDL);
        const float* src = lu + D * NDL;
        #pragma unroll
        for (int j = 0; j < 5; ++j)
            dst[j] = (uint32_tt)f2bf(src[2 * j]) | ((uint32_tt)f2bf(src[2 * j + 1]) << 16);
    }

    // ---- zero pads (k==9 block only) ----
    if (k == NK - 1) {
        for (int p = tid; p < 12 * ND; p += 256) {
            int n = p >> 8, D = p & 255;
            u1[((size_t)r * NP + 100 + n) * ND + D] = 0;
        }
        uint32_tt* u2u = (uint32_tt*)u2;
        #pragma unroll
        for (int j = 0; j < 14; ++j)
            u2u[((size_t)r * ND + tid) * (NP2 / 2) + 50 + j] = 0;
    }
}

// =====================================================================
// Main MFMA kernel, grid 512 x 256 threads, 2 blocks/CU co-resident.
// bid&7 = XCD slot: same-XCD blocks share a b-range (L2 locality).
// Direct-global A/B fragments; LDS for z / wTb / out-transpose.
// Phase 1: Z^T = U1 . X^T   (M=n 112, N=b 64, K=D 256)
// Phase 3: Out^T = U2 . W^T (M=D 256, N=b 64, K=n 128), then LDS
// transpose -> 512B-contiguous nontemporal stores (kills write amp).
// =====================================================================
__global__ __launch_bounds__(256, 2) void ksub_mfma3(const char* __restrict__ ws,
                                                     float* __restrict__ out) {
    __shared__ __align__(16) char smem[37824];
    float*    zbuf = (float*)smem;               // [64][100] fp32
    ushort_t* wTb  = (ushort_t*)smem;            // [64][136] bf16 (overlay)
    float*    ot   = (float*)smem;               // [64][132] fp32 (overlay, epilogue)
    float*    gp   = (float*)(smem + 33792);     // [1000] fp32

    const int tid  = threadIdx.x;
    const int w    = tid >> 6;
    const int lane = tid & 63;
    const int c    = lane & 15;
    const int q    = lane >> 4;
    const int bid  = blockIdx.x;
    // XCD-aware: xcd = bid&7 owns b-groups [xcd*8, xcd*8+8) across all r
    const int xcd  = bid & 7;
    const int j    = bid >> 3;                   // 0..63
    const int r    = j & 7;
    const int b0   = (xcd * 8 + (j >> 3)) * 64;
    const int bloc = w * 16 + c;

    const ushort_t* xb  = (const ushort_t*)(ws + WS_XB) + (size_t)(b0 + bloc) * ND + q * 8;
    const ushort_t* u1g = (const ushort_t*)(ws + WS_U1) + (size_t)r * NP * ND + c * ND + q * 8;
    const ushort_t* u2g = (const ushort_t*)(ws + WS_U2) + (size_t)r * ND * NP2 + c * NP2 + q * 8;
    const float*    gpg = (const float*)(ws + WS_GP) + (size_t)r * 1000;

    for (int i = tid; i < 1000; i += 256) gp[i] = gpg[i];

    // ---------------- phase 1: direct-global fragments ----------------
    bf16x8 xfr[8];
    #pragma unroll
    for (int Dc = 0; Dc < 8; ++Dc)
        xfr[Dc] = *(const bf16x8*)(xb + Dc * 32);

    f32x4 acc1[7];
    #pragma unroll
    for (int t = 0; t < 7; ++t) acc1[t] = (f32x4){0.f, 0.f, 0.f, 0.f};

    #pragma unroll
    for (int Dc = 0; Dc < 8; ++Dc) {
        bf16x8 a[7];
        #pragma unroll
        for (int t = 0; t < 7; ++t)
            a[t] = *(const bf16x8*)(u1g + t * 16 * ND + Dc * 32);
        #pragma unroll
        for (int t = 0; t < 7; ++t)
            acc1[t] = __builtin_amdgcn_mfma_f32_16x16x32_bf16(a[t], xfr[Dc], acc1[t], 0, 0, 0);
    }

    // ---- dump Z^T C-frags: row n = t*16+q*4+reg, col b = bloc ----
    #pragma unroll
    for (int t = 0; t < 7; ++t) {
        #pragma unroll
        for (int rg = 0; rg < 4; ++rg) {
            int n = t * 16 + q * 4 + rg;
            if (n < NN) zbuf[bloc * 100 + n] = acc1[t][rg];
        }
    }
    __syncthreads();

    // ---------------- softmax: b = tid>>2, k split on 4 lanes ----------------
    const int bsm = tid >> 2;
    const int kq  = tid & 3;
    float zk[3][10], ee[3];
    {
        const float* zr = zbuf + bsm * 100;
        float L[3];
        #pragma unroll
        for (int jj = 0; jj < 3; ++jj) {
            int k = kq + 4 * jj;
            L[jj] = -1e30f;
            if (k < NK) {
                #pragma unroll
                for (int d = 0; d < 10; ++d) zk[jj][d] = zr[k * 10 + d];
                const float* g = gp + k * 100;
                float acc = 0.f;
                #pragma unroll
                for (int d1 = 0; d1 < 10; ++d1) {
                    float t2 = 0.f;
                    #pragma unroll
                    for (int d2 = 0; d2 < 10; ++d2) t2 += g[d1 * 10 + d2] * zk[jj][d2];
                    acc += t2 * zk[jj][d1];
                }
                L[jj] = acc;
            }
        }
        float m = fmaxf(fmaxf(L[0], L[1]), L[2]);
        m = fmaxf(m, __shfl_xor(m, 1));
        m = fmaxf(m, __shfl_xor(m, 2));
        float s = 0.f;
        #pragma unroll
        for (int jj = 0; jj < 3; ++jj) {
            ee[jj] = (kq + 4 * jj < NK) ? __expf(L[jj] - m) : 0.f;
            s += ee[jj];
        }
        s += __shfl_xor(s, 1);
        s += __shfl_xor(s, 2);
        float inv = 1.0f / s;
        #pragma unroll
        for (int jj = 0; jj < 3; ++jj) ee[jj] *= inv;
    }
    __syncthreads();               // all zbuf reads done; wTb overlay safe

    #pragma unroll
    for (int jj = 0; jj < 3; ++jj) {
        int k = kq + 4 * jj;
        if (k < NK) {
            #pragma unroll
            for (int d = 0; d < 10; ++d)
                wTb[bsm * 136 + k * 10 + d] = f2bf(ee[jj] * zk[jj][d]);
        }
    }
    // zero-pad wTb n in [100,128): 14 uints per row
    for (int i = tid; i < 1024; i += 256) {
        int p = i & 15;
        if (p < 14) ((uint32_tt*)wTb)[(i >> 4) * 68 + 50 + p] = 0;
    }
    __syncthreads();

    // ---------------- phase 3: direct-global A, LDS B ----------------
    f32x4 acc3[16];
    #pragma unroll
    for (int t = 0; t < 16; ++t) acc3[t] = (f32x4){0.f, 0.f, 0.f, 0.f};

    #pragma unroll
    for (int nc = 0; nc < 4; ++nc) {
        bf16x8 bfr = *(const bf16x8*)(wTb + bloc * 136 + nc * 32 + q * 8);
        #pragma unroll
        for (int h = 0; h < 2; ++h) {
            bf16x8 a[8];
            #pragma unroll
            for (int jj = 0; jj < 8; ++jj)
                a[jj] = *(const bf16x8*)(u2g + (h * 8 + jj) * 16 * NP2 + nc * 32);
            #pragma unroll
            for (int jj = 0; jj < 8; ++jj)
                acc3[h * 8 + jj] = __builtin_amdgcn_mfma_f32_16x16x32_bf16(a[jj], bfr, acc3[h * 8 + jj], 0, 0, 0);
        }
    }

    // ---- epilogue: LDS transpose -> fully coalesced 512B stores ----
    const size_t orow = (size_t)r * NB + b0;
    #pragma unroll
    for (int h = 0; h < 2; ++h) {
        __syncthreads();           // wTb / previous-chunk reads complete
        #pragma unroll
        for (int dt2 = 0; dt2 < 8; ++dt2)
            *(f32x4*)(ot + bloc * 132 + dt2 * 16 + q * 4) = acc3[h * 8 + dt2];
        __syncthreads();
        #pragma unroll
        for (int i = 0; i < 8; ++i) {
            int g4 = i * 256 + tid;        // float4 index in 64x128 chunk
            int b  = g4 >> 5;
            int c4 = g4 & 31;
            f32x4 v = *(const f32x4*)(ot + b * 132 + c4 * 4);
            __builtin_nontemporal_store(v, (f32x4*)(out + (orow + b) * ND + h * 128 + c4 * 4));
        }
    }
}

// =====================================================================
// Fallback (round-2 verified path) if ws is too small for bf16 buffers
// =====================================================================
#define XS_S 68
#define US_S 132
#define ZB_S 104
#define WT_S 68
#define U2_S 68
#define OFF_WT 0
#define OFF_SH 6800
#define OFF_GP 13600
#define SMEM_F 14600

__global__ __launch_bounds__(128) void gram_kernel(const float* __restrict__ Us,
                                                   float* __restrict__ Gp) {
    int rk = blockIdx.x;
    const float* U = Us + (size_t)rk * ND * NDL;
    __shared__ float u[ND * NDL];
    for (int i = threadIdx.x; i < ND * NDL; i += blockDim.x) u[i] = U[i];
    __syncthreads();
    int e = threadIdx.x;
    if (e < NDL * NDL) {
        int d1 = e / NDL, d2 = e % NDL;
        float acc = 0.f;
        #pragma unroll 8
        for (int Di = 0; Di < ND; ++Di)
            acc += u[Di * NDL + d1] * u[Di * NDL + d2];
        Gp[(size_t)rk * (NDL * NDL) + e] = (d1 == d2 ? 10.0f : 0.0f) - 5.0f * acc;
    }
}

__global__ __launch_bounds__(256, 2) void ksub_fused(const float* __restrict__ x,
                                                     const float* __restrict__ Us,
                                                     const float* __restrict__ Gp,
                                                     float* __restrict__ out) {
    __shared__ float smemf[SMEM_F];
    float* wT   = smemf + OFF_WT;
    float* xsf  = smemf + OFF_SH;
    float* usf  = smemf + OFF_SH + 2176;
    float* zbuf = smemf + OFF_SH;
    float* u2   = smemf + OFF_SH;
    float* gp   = smemf + OFF_GP;

    const int tid = threadIdx.x;
    const int r   = blockIdx.y;
    const int b0  = blockIdx.x * 64;

    for (int i = tid; i < NK * NDL * NDL; i += 256)
        gp[i] = Gp[(size_t)r * (NK * NDL * NDL) + i];

    const int nt = tid & 15;
    const int bt = tid >> 4;
    float acc[4][8];
    #pragma unroll
    for (int j = 0; j < 4; ++j)
        #pragma unroll
        for (int i = 0; i < 8; ++i) acc[j][i] = 0.f;

    for (int cch = 0; cch < 8; ++cch) {
        __syncthreads();
        for (int i = tid; i < 512; i += 256) {
            int b = i >> 3, f = i & 7;
            float4 v = ((const float4*)(x + (size_t)(b0 + b) * ND))[cch * 8 + f];
            float* dst = xsf + (f * 4) * XS_S + b;
            dst[0] = v.x; dst[XS_S] = v.y; dst[2 * XS_S] = v.z; dst[3 * XS_S] = v.w;
        }
        for (int p = tid; p < 320; p += 256) {
            int k = p >> 5, Dl = p & 31;
            const float* g = Us + ((size_t)((r * NK + k) * ND) + cch * 32 + Dl) * NDL;
            float* dst = usf + Dl * US_S + k * NDL;
            #pragma unroll
            for (int d = 0; d < 10; ++d) dst[d] = g[d];
        }
        __syncthreads();
        #pragma unroll 4
        for (int Dl = 0; Dl < 32; ++Dl) {
            float4 xv = *(const float4*)(xsf + Dl * XS_S + bt * 4);
            float4 ua = *(const float4*)(usf + Dl * US_S + nt * 8);
            float4 ub = *(const float4*)(usf + Dl * US_S + nt * 8 + 4);
            float xa[4] = {xv.x, xv.y, xv.z, xv.w};
            float uu[8] = {ua.x, ua.y, ua.z, ua.w, ub.x, ub.y, ub.z, ub.w};
            #pragma unroll
            for (int j = 0; j < 4; ++j)
                #pragma unroll
                for (int i = 0; i < 8; ++i) acc[j][i] += xa[j] * uu[i];
        }
    }
    __syncthreads();
    if (nt < 12) {
        #pragma unroll
        for (int j = 0; j < 4; ++j) {
            float* zp = zbuf + (bt * 4 + j) * ZB_S + nt * 8;
            *(float4*)(zp)     = make_float4(acc[j][0], acc[j][1], acc[j][2], acc[j][3]);
            *(float4*)(zp + 4) = make_float4(acc[j][4], acc[j][5], acc[j][6], acc[j][7]);
        }
    } else if (nt == 12) {
        #pragma unroll
        for (int j = 0; j < 4; ++j) {
            float* zp = zbuf + (bt * 4 + j) * ZB_S + 96;
            *(float4*)(zp) = make_float4(acc[j][0], acc[j][1], acc[j][2], acc[j][3]);
        }
    }
    __syncthreads();
    if (tid < 64) {
        const int b_l = tid;
        const float* zrow = zbuf + b_l * ZB_S;
        float L[10];
        #pragma unroll
        for (int k = 0; k < NK; ++k) {
            float zkk[10];
            #pragma unroll
            for (int d = 0; d < 10; ++d) zkk[d] = zrow[k * 10 + d];
            const float* g = gp + k * 100;
            float a2 = 0.f;
            #pragma unroll
            for (int d1 = 0; d1 < 10; ++d1) {
                float t = 0.f;
                #pragma unroll
                for (int d2 = 0; d2 < 10; ++d2) t += g[d1 * 10 + d2] * zkk[d2];
                a2 += t * zkk[d1];
            }
            L[k] = a2;
        }
        float m = L[0];
        #pragma unroll
        for (int k = 1; k < NK; ++k) m = fmaxf(m, L[k]);
        float e[10], s = 0.f;
        #pragma unroll
        for (int k = 0; k < NK; ++k) { e[k] = __expf(L[k] - m); s += e[k]; }
        float inv = 1.0f / s;
        #pragma unroll
        for (int k = 0; k < NK; ++k) {
            float ck = e[k] * inv;
            #pragma unroll
            for (int d = 0; d < 10; ++d)
                wT[(k * 10 + d) * WT_S + b_l] = ck * zrow[k * 10 + d];
        }
    }
    const int Dt  = tid & 15;
    const int bt2 = tid >> 4;
    for (int c2 = 0; c2 < 4; ++c2) {
        __syncthreads();
        for (int p = tid; p < 640; p += 256) {
            int k = p >> 6, Dl = p & 63;
            const float* g = Us + ((size_t)((r * NK + k) * ND) + c2 * 64 + Dl) * NDL;
            float* dst = u2 + (k * NDL) * U2_S + Dl;
            #pragma unroll
            for (int d = 0; d < 10; ++d) dst[d * U2_S] = g[d];
        }
        __syncthreads();
        float o[4][4];
        #pragma unroll
        for (int j = 0; j < 4; ++j)
            #pragma unroll
            for (int i = 0; i < 4; ++i) o[j][i] = 0.f;
        #pragma unroll 4
        for (int n = 0; n < NN; ++n) {
            float4 wv = *(const float4*)(wT + n * WT_S + bt2 * 4);
            float4 uv = *(const float4*)(u2 + n * U2_S + Dt * 4);
            float wa[4] = {wv.x, wv.y, wv.z, wv.w};
            float ub[4] = {uv.x, uv.y, uv.z, uv.w};
            #pragma unroll
            for (int j = 0; j < 4; ++j)
                #pragma unroll
                for (int i = 0; i < 4; ++i) o[j][i] += wa[j] * ub[i];
        }
        #pragma unroll
        for (int j = 0; j < 4; ++j) {
            float* op = out + ((size_t)r * NB + b0 + bt2 * 4 + j) * ND + c2 * 64 + Dt * 4;
            *(float4*)op = make_float4(o[j][0], o[j][1], o[j][2], o[j][3]);
        }
    }
}

extern "C" void kernel_launch(void* const* d_in, const int* in_sizes, int n_in,
                              void* d_out, int out_size, void* d_ws, size_t ws_size,
                              hipStream_t stream) {
    const float* x  = (const float*)d_in[0];
    const float* Us = (const float*)d_in[1];
    float* out = (float*)d_out;

    if (ws_size >= (size_t)WS_NEED) {
        prep_kernel<<<dim3(1104), 256, 0, stream>>>(x, Us, (char*)d_ws);
        ksub_mfma3<<<dim3(512), 256, 0, stream>>>((const char*)d_ws, out);
    } else {
        gram_kernel<<<dim3(NR * NK), 128, 0, stream>>>(Us, (float*)d_ws);
        ksub_fused<<<dim3(NB / 64, NR), 256, 0, stream>>>(x, Us, (float*)d_ws, out);
    }
}